// Round 4
// baseline (116.377 us; speedup 1.0000x reference)
//
#include <hip/hip_runtime.h>
#include <math.h>

// Problem constants (fixed by setup_inputs)
#define BATCH 8
#define HI 512
#define WI 512
#define HO 256
#define WO 256
#define PLANE (HI*WI)          // 262144 per channel
#define OPIX (HO*WO)           // 65536 output pixels per batch
// Block tile: 64 iw-cols x 8 ih-rows (2 rows per thread, 4 waves).
// Gather footprint for iw in [w0,w0+64): image rows/cols in [w0+2, w0+70).
#define LROWS 68
#define LCOLS 10
#define LQ 11                  // float4 per row: 10 data + 1 pad (176 B row, 16B-aligned)

__global__ __launch_bounds__(256, 3) void downsampler_kernel(
    const float* __restrict__ images,
    const float* __restrict__ kernels,
    const float* __restrict__ offx,
    const float* __restrict__ offy,
    float* __restrict__ out)
{
    __shared__ float4 simg[LROWS * LQ];   // 68*11*16 B = 11968 B

    const int blk  = blockIdx.x;          // 1024 blocks
    const int b    = blk >> 7;            // batch
    const int ihx  = (blk >> 2) & 31;     // ih-tile (8 rows each)
    const int w0   = (blk & 3) << 6;      // iw-tile base (64 cols)
    const int tid  = threadIdx.x;
    const int lane = tid & 63;
    const int g    = tid >> 6;            // wave id 0..3
    const int iw   = w0 + lane;

    // ---- Stage the 68x10 band as RGBX float4 into LDS ----
    // I(r, c, .) = simg[(r-(w0+2))*11 + (c-(r-4))], r in [w0+2, w0+70)
    {
        const float* imb = images + (size_t)b * 3 * PLANE;
        const int total = LROWS * LCOLS;   // 680
        for (int i = tid; i < total; i += 256) {
            const int row = i / LCOLS;
            const int col = i - row * LCOLS;
            const int r = w0 + 2 + row;
            int c = r - 4 + col;
            c = c < 0 ? 0 : c;   // upper clamp provably inactive (c <= 266)
            const float* src = imb + r * WI + c;
            simg[row * LQ + col] =
                make_float4(src[0], src[PLANE], src[2 * PLANE], 0.0f);
        }
    }
    __syncthreads();

    const bool flip = (ihx < 16);          // ih < 128, uniform per block
    const float* offxb = offx    + (size_t)b * 9 * OPIX;
    const float* offyb = offy    + (size_t)b * 9 * OPIX;
    const float* kernb = kernels + (size_t)b * 9 * OPIX;

    const float uu_own = (float)iw + 0.5f;
    const float uu_s0  = (float)((2 * iw) & 255) + 0.5f;  // u at scrambled pixel 2pl
    const float uu_s1  = uu_s0 + 1.0f;                     // u at pixel 2pl+1 (no wrap: even<=254)

    const float TWO_PI_INV = 0.15915494309189533577f;

    // ---- Batch ALL global loads for both pixels up front ----
    float  ox[2][9], oy[2][9], kv[2][9];
    float2 sx[2][9], sy[2][9];
    int    pls[2];
    #pragma unroll
    for (int p = 0; p < 2; ++p) {
        const int ih = (ihx << 3) + (g << 1) + p;
        const int pl = ih * WO + iw;
        pls[p] = pl;
        const int pix2 = pl & (OPIX / 2 - 1);   // float2 index of scrambled pair (2pl, 2pl+1)
        #pragma unroll
        for (int ks = 0; ks < 9; ++ks) {
            ox[p][ks] = offxb[ks * OPIX + pl];
            oy[p][ks] = offyb[ks * OPIX + pl];
            kv[p][ks] = kernb[ks * OPIX + pl];
            sx[p][ks] = ((const float2*)(offxb + ks * OPIX))[pix2];
            sy[p][ks] = ((const float2*)(offyb + ks * OPIX))[pix2];
        }
    }

    #pragma unroll
    for (int p = 0; p < 2; ++p) {
        const int pl = pls[p];
        float acc0 = 0.f, acc1 = 0.f, acc2 = 0.f;

        #pragma unroll
        for (int k = 0; k < 9; ++k) {
            // ---- own coords -> gather corners ----
            const float kxf = (float)(k / 3);
            const float kyf = (float)(k - 3 * (k / 3));
            const float cx = ((ox[p][k] + 1.5f) + kxf) + uu_own;
            const float cy = ((oy[p][k] + 1.5f) + kyf) + uu_own;
            const int x0 = (int)floorf(cx);   // row in [iw+2, iw+5]
            const int y0 = (int)floorf(cy);   // col in [iw+2, iw+5]

            const int rowrel = x0 - 2 - w0;        // [lane, lane+3]
            const int colq   = y0 - x0 + 4;        // [1, 7]
            const float4* q0 = &simg[rowrel * LQ]; // row x0
            const float4* q1 = q0 + LQ;            // row x1 = x0+1
            const float4 Ia = q0[colq];            // (x0,y0)
            const float4 Ib = q0[colq + 1];        // (x0,y1)
            const float4 Ic = q1[colq - 1];        // (x1,y0)
            const float4 Id = q1[colq];            // (x1,y1)

            // ---- scrambled weights for taps t=2k, 2k+1 ----
            const int ta = 2 * k,      tb = 2 * k + 1;
            const int sel_a = (ta >= 9) ? 1 : 0;
            const int sel_b = (tb >= 9) ? 1 : 0;
            const int ks_a = ta - 9 * sel_a;
            const int ks_b = tb - 9 * sel_b;
            const float uu_a = sel_a ? uu_s1 : uu_s0;
            const float uu_b = sel_b ? uu_s1 : uu_s0;
            const float oxa = sel_a ? sx[p][ks_a].y : sx[p][ks_a].x;
            const float oya = sel_a ? sy[p][ks_a].y : sy[p][ks_a].x;
            const float oxb2 = sel_b ? sx[p][ks_b].y : sx[p][ks_b].x;
            const float oyb2 = sel_b ? sy[p][ks_b].y : sy[p][ks_b].x;
            const float kxa = (float)(ks_a / 3), kya = (float)(ks_a - 3 * (ks_a / 3));
            const float kxb = (float)(ks_b / 3), kyb = (float)(ks_b - 3 * (ks_b / 3));

            // reference fp32 op order: ((off + 1.5) + k?) + u
            const float cxa = ((oxa + 1.5f) + kxa) + uu_a;
            const float cya = ((oya + 1.5f) + kya) + uu_a;
            const float cxb = ((oxb2 + 1.5f) + kxb) + uu_b;
            const float cyb = ((oyb2 + 1.5f) + kyb) + uu_b;
            const float fxa = cxa - floorf(cxa);   // exact (Sterbenz)
            const float fya = cya - floorf(cya);
            const float fxb = cxb - floorf(cxb);
            const float fyb = cyb - floorf(cyb);
            const float w0w = flip ? (1.0f - fxa) : fxa;   // wx[2k]
            const float w1w = flip ? (1.0f - fxb) : fxb;   // wx[2k+1]
            const float v0w = flip ? (1.0f - fya) : fya;   // wy[2k]
            const float v1w = flip ? (1.0f - fyb) : fyb;   // wy[2k+1]

            const float w0v0 = w0w * v0w, w1v0 = w1w * v0w;
            const float w0v1 = w0w * v1w, w1v1 = w1w * v1w;

            // scrambled channel/corner table
            const float p0 = w0v0 * Ib.x + w1v0 * Ic.x + w0v1 * Id.y + w1v1 * Ia.z;
            const float p1 = w0v0 * Ia.x + w1v0 * Ib.y + w0v1 * Ic.y + w1v1 * Id.z;
            const float p2 = w0v0 * Id.x + w1v0 * Ia.y + w0v1 * Ib.z + w1v1 * Ic.z;

            acc0 += kv[p][k] * p0;
            acc1 += kv[p][k] * p1;
            acc2 += kv[p][k] * p2;
        }

        // ---- softround(out * 255) via HW sin (input in revolutions) ----
        const size_t obase = ((size_t)b * OPIX + (size_t)pl) * 3;
        const float z0 = acc0 * 255.0f;
        const float z1 = acc1 * 255.0f;
        const float z2 = acc2 * 255.0f;
        const float r0s = z0 - rintf(z0);   // exact; sin(2*pi*z) = sin(2*pi*r)
        const float r1s = z1 - rintf(z1);
        const float r2s = z2 - rintf(z2);
        out[obase + 0] = z0 - __builtin_amdgcn_sinf(r0s) * TWO_PI_INV;
        out[obase + 1] = z1 - __builtin_amdgcn_sinf(r1s) * TWO_PI_INV;
        out[obase + 2] = z2 - __builtin_amdgcn_sinf(r2s) * TWO_PI_INV;
    }
}

extern "C" void kernel_launch(void* const* d_in, const int* in_sizes, int n_in,
                              void* d_out, int out_size, void* d_ws, size_t ws_size,
                              hipStream_t stream) {
    const float* images  = (const float*)d_in[0];
    const float* kernels = (const float*)d_in[1];
    const float* offx    = (const float*)d_in[2];
    const float* offy    = (const float*)d_in[3];
    float* out = (float*)d_out;

    dim3 grid(BATCH * 32 * 4);   // 1024 blocks: (b, ih-tile of 8, iw-tile of 64)
    dim3 block(256);             // 64 iw-lanes x 4 waves, 2 ih-rows per thread
    hipLaunchKernelGGL(downsampler_kernel, grid, block, 0, stream,
                       images, kernels, offx, offy, out);
}